// Round 2
// baseline (206.536 us; speedup 1.0000x reference)
//
#include <hip/hip_runtime.h>

#define BATCH   65536
#define STEPS   200
#define TCHUNK  8
#define NCHUNK  (STEPS / TCHUNK)   // 25
#define REP     4                  // replica waves per 64-element group
#define BLK     (64 * REP)         // 256 threads, 4 waves/block
#define LSTRIDE 36                 // dwords per lane row: 144 B, float4-aligned

// One SEIR step. Bit-identical to the passing (absmax=16.0) kernels.
__device__ __forceinline__ void seir_step(float4& x, float A, float B, float C, float invN)
{
    float infl = B * x.x * (x.y + x.z) * invN;
    float ae = A * x.y;
    float ci = C * x.z;
    float d0 = -infl;
    float d1 = infl - ae;
    float d2 = ae - ci;
    float d3 = ci;
    d0 = fminf(fmaxf(d0, -100000.0f), 100000.0f);
    d1 = fminf(fmaxf(d1, -100000.0f), 100000.0f);
    d2 = fminf(fmaxf(d2, -100000.0f), 100000.0f);
    d3 = fminf(fmaxf(d3, -100000.0f), 100000.0f);
    x.x += 0.5f * d0;
    x.y += 0.5f * d1;
    x.z += 0.5f * d2;
    x.w += 0.5f * d3;
}

// Decomposition: block = 64 batch elements x REP replica waves.
// Every wave runs the FULL 200-step recurrence for all 64 elements
// (lane = element; redundant compute is ~4 us vs a ~32 us write floor),
// but wave w only stages+stores chunks with (c % REP == w).
//  -> 4096 waves total (16/CU, 4/SIMD) instead of 1024 (1/SIMD):
//     4x the latency-hiding for the store stream, zero inter-wave
//     communication, zero barriers, bytes written unchanged.
__global__ __launch_bounds__(BLK) void seir_kernel(
    const float* __restrict__ init,
    const float* __restrict__ w,
    float* __restrict__ out)
{
    __shared__ float lds[REP][64 * LSTRIDE];   // 4 x 9216 B = 36.9 KB

    const int tid    = threadIdx.x;
    const int wv     = tid >> 6;               // replica id 0..3 (wave-uniform)
    const int lane   = tid & 63;               // element within group
    const int base_b = blockIdx.x * 64;
    const int b      = base_b + lane;

    // flush geometry: lane group of 8 covers one element's 8 consecutive
    // float4 (128 B contiguous) -> each store instr writes 16 FULL 64B lines.
    const int jj    = lane & 7;
    const int bbase = lane >> 3;

    const float A = w[4];
    const float B = w[5];
    const float C = w[6];
    const float invN = 1.0f / 100000.0f;

    float4 x = reinterpret_cast<const float4*>(init)[b];
    float4* outf4 = reinterpret_cast<float4*>(out);
    float* buf = lds[wv];                      // private per-wave buffer

    for (int c = 0; c < NCHUNK; ++c) {
        if ((c & (REP - 1)) == wv) {
            // --- owned chunk: compute + stash each step (ds_write_b128) ---
            // write banks: 4-bank group = (lane + tt) & 7 -> 8 lanes/group, free
            #pragma unroll
            for (int tt = 0; tt < TCHUNK; ++tt) {
                seir_step(x, A, B, C, invN);
                *reinterpret_cast<float4*>(&buf[lane * LSTRIDE + tt * 4]) = x;
            }
            // --- coalesced flush: 8 ds_read_b128 + 8 global_store_dwordx4 ---
            // Stores stay in flight under the next 3 (non-owned) compute chunks;
            // buf isn't rewritten for another REP chunks -> no hazard, no barrier.
            const int t0 = c * TCHUNK;
            float4 f[8];
            #pragma unroll
            for (int k = 0; k < 8; ++k) {
                const int bb = k * 8 + bbase;
                // read banks: 4-bank group = (bb + jj) & 7, uniform -> free
                f[k] = *reinterpret_cast<const float4*>(&buf[bb * LSTRIDE + jj * 4]);
            }
            #pragma unroll
            for (int k = 0; k < 8; ++k) {
                const int bb = k * 8 + bbase;
                outf4[(size_t)(base_b + bb) * STEPS + t0 + jj] = f[k];
            }
        } else {
            // --- non-owned chunk: advance the recurrence only ---
            #pragma unroll
            for (int tt = 0; tt < TCHUNK; ++tt)
                seir_step(x, A, B, C, invN);
        }
    }
}

extern "C" void kernel_launch(void* const* d_in, const int* in_sizes, int n_in,
                              void* d_out, int out_size, void* d_ws, size_t ws_size,
                              hipStream_t stream) {
    const float* init = (const float*)d_in[0];
    const float* w    = (const float*)d_in[1];
    float* out        = (float*)d_out;

    seir_kernel<<<dim3(BATCH / 64), dim3(BLK), 0, stream>>>(init, w, out);
}